// Round 3
// baseline (1528.750 us; speedup 1.0000x reference)
//
#include <hip/hip_runtime.h>
#include <hip/hip_bf16.h>

#define N_NODES 100000
#define N_EDGES 1600000
#define IN_C 128
#define C 64            // hid_c == out_c

__device__ __forceinline__ float bfu2f(unsigned short u) {
    return __uint_as_float(((unsigned int)u) << 16);
}

// ---- runtime dtype detection (deterministic, same work every call) --------
// flags[0] = 1 if float arrays are fp32, 0 if bf16.
//   bf16 data never has exponent field 0xFF (no inf/NaN in inputs); fp32 data
//   read as ushorts exposes random mantissa halves -> 0xFF w.p. 1/256 each.
// flags[1] = 1 if edge_index is int64, 0 if int32.
//   int64 indices < 2^31 have all-zero high halves at odd int32 positions.
__global__ __launch_bounds__(256) void k_detect(
    const unsigned short* __restrict__ x16, const int* __restrict__ ei32,
    int* __restrict__ flags)
{
    __shared__ int cff, cnz;
    int t = threadIdx.x;
    if (t == 0) { cff = 0; cnz = 0; }
    __syncthreads();
    int lff = 0;
    for (int i = t; i < 65536; i += 256) {        // 128KB of x: in-bounds either way
        unsigned short u = x16[i];
        if (((u >> 7) & 0xFF) == 0xFF) lff++;
    }
    int lnz = 0;
    for (int i = t; i < 2048; i += 256) {         // 16KB of edge_index
        if (ei32[2 * i + 1] != 0) lnz++;
    }
    if (lff) atomicAdd(&cff, lff);
    if (lnz) atomicAdd(&cnz, lnz);
    __syncthreads();
    if (t == 0) {
        flags[0] = (cff > 0) ? 1 : 0;
        flags[1] = (cnz == 0) ? 1 : 0;
    }
}

__device__ __forceinline__ float load_f(const void* p, int i, int f32) {
    return f32 ? ((const float*)p)[i] : bfu2f(((const unsigned short*)p)[i]);
}
__device__ __forceinline__ int load_idx(const void* ei, size_t i, int i64) {
    return i64 ? (int)((const long long*)ei)[i] : ((const int*)ei)[i];
}

// ---- softmax denominator: ssum[dst] += exp(edge_attr) ---------------------
// edge_attr in [0,1) so max-subtraction is unnecessary (no overflow).
__global__ __launch_bounds__(256) void k_edge_exp(
    const void* __restrict__ ea, const void* __restrict__ ei,
    const int* __restrict__ flags, float* __restrict__ ssum)
{
    int e = blockIdx.x * 256 + threadIdx.x;      // grid is exactly E/256
    float l = load_f(ea, e, flags[0]);
    int d = load_idx(ei, (size_t)N_EDGES + e, flags[1]);
    atomicAdd(&ssum[d], expf(l));
}

// ---- GEMM1: xw[n,c] = sum_k x[n,k] * W1[c,k] ------------------------------
__global__ __launch_bounds__(256) void k_gemm1(
    const void* __restrict__ x, const void* __restrict__ W,
    const int* __restrict__ flags, float* __restrict__ xw)
{
    __shared__ float xs[4 * IN_C];
    int t = threadIdx.x;
    int f32 = flags[0];
    int base = blockIdx.x * 4 * IN_C;
    if (f32) {
        const float* xp = (const float*)x;
        for (int i = t; i < 4 * IN_C; i += 256) xs[i] = xp[base + i];
    } else {
        const unsigned short* xp = (const unsigned short*)x;
        for (int i = t; i < 4 * IN_C; i += 256) xs[i] = bfu2f(xp[base + i]);
    }
    __syncthreads();
    int node = t >> 6, col = t & 63;
    const float* xr = xs + node * IN_C;
    float acc = 0.f;
    if (f32) {
        const float* wr = (const float*)W + col * IN_C;
        #pragma unroll
        for (int k = 0; k < IN_C; k += 4) {
            float4 w = *(const float4*)(wr + k);
            float4 xv = *(const float4*)(xr + k);
            acc += xv.x * w.x + xv.y * w.y + xv.z * w.z + xv.w * w.w;
        }
    } else {
        const unsigned short* wr = (const unsigned short*)W + col * IN_C;
        #pragma unroll
        for (int k = 0; k < IN_C; k += 4) {
            ushort4 w = *(const ushort4*)(wr + k);
            float4 xv = *(const float4*)(xr + k);
            acc += xv.x * bfu2f(w.x) + xv.y * bfu2f(w.y)
                 + xv.z * bfu2f(w.z) + xv.w * bfu2f(w.w);
        }
    }
    xw[blockIdx.x * 4 * C + node * C + col] = acc;
}

// ---- GEMM2: xw[n,c] = sum_k h[n,k] * W2[c,k]  (h is f32 in ws) ------------
// Safe IN-PLACE (h == xw): each block reads only its own 4 rows into LDS
// before writing those same 4 rows.
__global__ __launch_bounds__(256) void k_gemm2(
    const float* __restrict__ h, const void* __restrict__ W,
    const int* __restrict__ flags, float* __restrict__ xw)
{
    __shared__ float xs[4 * C];
    int t = threadIdx.x;
    int base = blockIdx.x * 4 * C;
    xs[t] = h[base + t];
    __syncthreads();
    int node = t >> 6, col = t & 63;
    const float* xr = xs + node * C;
    float acc = 0.f;
    if (flags[0]) {
        const float* wr = (const float*)W + col * C;
        #pragma unroll
        for (int k = 0; k < C; k += 4) {
            float4 w = *(const float4*)(wr + k);
            float4 xv = *(const float4*)(xr + k);
            acc += xv.x * w.x + xv.y * w.y + xv.z * w.z + xv.w * w.w;
        }
    } else {
        const unsigned short* wr = (const unsigned short*)W + col * C;
        #pragma unroll
        for (int k = 0; k < C; k += 4) {
            ushort4 w = *(const ushort4*)(wr + k);
            float4 xv = *(const float4*)(xr + k);
            acc += xv.x * bfu2f(w.x) + xv.y * bfu2f(w.y)
                 + xv.z * bfu2f(w.z) + xv.w * bfu2f(w.w);
        }
    }
    xw[base + node * C + col] = acc;
}

// ---- per-edge message: aggr[dst] += att * xw[src]  (wave per edge) --------
__global__ __launch_bounds__(256) void k_msg(
    const float* __restrict__ xw, const void* __restrict__ ea,
    const float* __restrict__ ssum, const void* __restrict__ ei,
    const int* __restrict__ flags, float* __restrict__ aggr)
{
    int e = blockIdx.x * 4 + (threadIdx.x >> 6);
    int lane = threadIdx.x & 63;
    int s = load_idx(ei, (size_t)e, flags[1]);
    int d = load_idx(ei, (size_t)N_EDGES + e, flags[1]);
    float a = expf(load_f(ea, e, flags[0])) / ssum[d];
    atomicAdd(&aggr[d * C + lane], a * xw[s * C + lane]);
}

// ---- update1: xw = sigmoid(aggr + xw + b) in-place; re-zero aggr ----------
__global__ __launch_bounds__(256) void k_update1(
    float* __restrict__ aggr, float* __restrict__ xw,
    const void* __restrict__ b, const int* __restrict__ flags)
{
    int i = blockIdx.x * 256 + threadIdx.x;
    float v = aggr[i] + xw[i] + load_f(b, i & 63, flags[0]);
    xw[i] = 1.f / (1.f + expf(-v));
    aggr[i] = 0.f;
}

// ---- update2: out = sigmoid(aggr + xw + b), dtype per flag ----------------
__global__ __launch_bounds__(256) void k_update2(
    const float* __restrict__ aggr, const float* __restrict__ xw,
    const void* __restrict__ b, const int* __restrict__ flags,
    void* __restrict__ out)
{
    int i = blockIdx.x * 256 + threadIdx.x;
    float v = aggr[i] + xw[i] + load_f(b, i & 63, flags[0]);
    float r = 1.f / (1.f + expf(-v));
    if (flags[0]) ((float*)out)[i] = r;
    else ((__hip_bfloat16*)out)[i] = __float2bfloat16(r);
}

extern "C" void kernel_launch(void* const* d_in, const int* in_sizes, int n_in,
                              void* d_out, int out_size, void* d_ws, size_t ws_size,
                              hipStream_t stream) {
    const void* x  = d_in[0];    // [N,128] bf16 or f32
    const void* ei = d_in[1];    // [2,E] int32 or int64
    const void* ea = d_in[2];    // [E]
    const void* W1 = d_in[3];    // [64,128]
    const void* b1 = d_in[4];    // [64]
    const void* W2 = d_in[5];    // [64,64]
    const void* b2 = d_in[6];    // [64]

    int*   flags = (int*)d_ws;
    float* ssum  = (float*)((char*)d_ws + 256);   // N
    float* xw    = ssum + N_NODES;                // N*64 (also holds h1 in-place)
    float* aggr  = xw + (size_t)N_NODES * C;      // N*64
    // total ws use: 256 + (N + 2*N*64)*4 = ~51.6 MB

    k_detect<<<1, 256, 0, stream>>>((const unsigned short*)x, (const int*)ei, flags);

    // zero ssum + xw + aggr in one contiguous memset (gemm1 overwrites xw)
    hipMemsetAsync(ssum, 0, ((size_t)N_NODES + 2 * (size_t)N_NODES * C) * sizeof(float), stream);

    // shared attention denominator (edge_attr/dst identical for both layers)
    k_edge_exp<<<N_EDGES / 256, 256, 0, stream>>>(ea, ei, flags, ssum);

    // layer 1
    k_gemm1<<<N_NODES / 4, 256, 0, stream>>>(x, W1, flags, xw);
    k_msg<<<N_EDGES / 4, 256, 0, stream>>>(xw, ea, ssum, ei, flags, aggr);
    k_update1<<<(N_NODES * C) / 256, 256, 0, stream>>>(aggr, xw, b1, flags);

    // layer 2 (gemm2 in-place on xw)
    k_gemm2<<<N_NODES / 4, 256, 0, stream>>>(xw, W2, flags, xw);
    k_msg<<<N_EDGES / 4, 256, 0, stream>>>(xw, ea, ssum, ei, flags, aggr);
    k_update2<<<(N_NODES * C) / 256, 256, 0, stream>>>(aggr, xw, b2, flags, d_out);
}

// Round 4
// 1302.438 us; speedup vs baseline: 1.1738x; 1.1738x over previous
//
#include <hip/hip_runtime.h>
#include <hip/hip_bf16.h>

#define N_NODES 100000
#define N_EDGES 1600000
#define IN_C 128
#define C 64            // hid_c == out_c

__device__ __forceinline__ float bfu2f(unsigned short u) {
    return __uint_as_float(((unsigned int)u) << 16);
}
__device__ __forceinline__ float load_f(const void* p, int i, int f32) {
    return f32 ? ((const float*)p)[i] : bfu2f(((const unsigned short*)p)[i]);
}
__device__ __forceinline__ int load_idx(const void* ei, size_t i, int i64) {
    return i64 ? (int)((const long long*)ei)[i] : ((const int*)ei)[i];
}

// ---- runtime dtype detection (R3 confirmed bf16+int32; kept for safety) ---
__global__ __launch_bounds__(256) void k_detect(
    const unsigned short* __restrict__ x16, const int* __restrict__ ei32,
    int* __restrict__ flags)
{
    __shared__ int cff, cnz;
    int t = threadIdx.x;
    if (t == 0) { cff = 0; cnz = 0; }
    __syncthreads();
    int lff = 0;
    for (int i = t; i < 65536; i += 256) {
        unsigned short u = x16[i];
        if (((u >> 7) & 0xFF) == 0xFF) lff++;
    }
    int lnz = 0;
    for (int i = t; i < 2048; i += 256) {
        if (ei32[2 * i + 1] != 0) lnz++;
    }
    if (lff) atomicAdd(&cff, lff);
    if (lnz) atomicAdd(&cnz, lnz);
    __syncthreads();
    if (t == 0) {
        flags[0] = (cff > 0) ? 1 : 0;   // 1 = fp32 floats
        flags[1] = (cnz == 0) ? 1 : 0;  // 1 = int64 indices
    }
}

// ---- CSR pass A: degree histogram + softmax denominator -------------------
__global__ __launch_bounds__(256) void k_hist(
    const void* __restrict__ ea, const void* __restrict__ ei,
    const int* __restrict__ flags, float* __restrict__ ssum, int* __restrict__ cnt)
{
    int e = blockIdx.x * 256 + threadIdx.x;
    int d = load_idx(ei, (size_t)N_EDGES + e, flags[1]);
    atomicAdd(&ssum[d], expf(load_f(ea, e, flags[0])));
    atomicAdd(&cnt[d], 1);
}

// ---- CSR pass B: one-block exclusive scan cnt -> row_ptr, next ------------
__global__ __launch_bounds__(256) void k_scan(
    const int* __restrict__ cnt, int* __restrict__ row_ptr, int* __restrict__ next)
{
    __shared__ int part[256];
    int t = threadIdx.x;
    const int CH = (N_NODES + 255) / 256;   // 391
    int beg = t * CH, end = min(beg + CH, N_NODES);
    int s = 0;
    for (int i = beg; i < end; ++i) s += cnt[i];
    part[t] = s;
    for (int off = 1; off < 256; off <<= 1) {
        __syncthreads();
        int v = (t >= off) ? part[t - off] : 0;
        __syncthreads();
        part[t] += v;
    }
    __syncthreads();
    int run = (t == 0) ? 0 : part[t - 1];
    for (int i = beg; i < end; ++i) {
        row_ptr[i] = run; next[i] = run;
        run += cnt[i];
    }
    if (t == 255) row_ptr[N_NODES] = part[255];
}

// ---- CSR pass C: scatter {src, att} sorted by dst -------------------------
__global__ __launch_bounds__(256) void k_scatter(
    const void* __restrict__ ea, const void* __restrict__ ei,
    const int* __restrict__ flags, const float* __restrict__ ssum,
    int* __restrict__ next, int2* __restrict__ srt)
{
    int e = blockIdx.x * 256 + threadIdx.x;
    int s = load_idx(ei, (size_t)e, flags[1]);
    int d = load_idx(ei, (size_t)N_EDGES + e, flags[1]);
    float w = expf(load_f(ea, e, flags[0])) / ssum[d];
    int pos = atomicAdd(&next[d], 1);
    srt[pos] = make_int2(s, __float_as_int(w));
}

// ---- GEMM1: xw[n,c] = sum_k x[n,k] * W1[c,k] ------------------------------
__global__ __launch_bounds__(256) void k_gemm1(
    const void* __restrict__ x, const void* __restrict__ W,
    const int* __restrict__ flags, float* __restrict__ xw)
{
    __shared__ float xs[4 * IN_C];
    int t = threadIdx.x;
    int f32 = flags[0];
    int base = blockIdx.x * 4 * IN_C;
    if (f32) {
        const float* xp = (const float*)x;
        for (int i = t; i < 4 * IN_C; i += 256) xs[i] = xp[base + i];
    } else {
        const unsigned short* xp = (const unsigned short*)x;
        for (int i = t; i < 4 * IN_C; i += 256) xs[i] = bfu2f(xp[base + i]);
    }
    __syncthreads();
    int node = t >> 6, col = t & 63;
    const float* xr = xs + node * IN_C;
    float acc = 0.f;
    if (f32) {
        const float* wr = (const float*)W + col * IN_C;
        #pragma unroll
        for (int k = 0; k < IN_C; k += 4) {
            float4 w = *(const float4*)(wr + k);
            float4 xv = *(const float4*)(xr + k);
            acc += xv.x * w.x + xv.y * w.y + xv.z * w.z + xv.w * w.w;
        }
    } else {
        const unsigned short* wr = (const unsigned short*)W + col * IN_C;
        #pragma unroll
        for (int k = 0; k < IN_C; k += 4) {
            ushort4 w = *(const ushort4*)(wr + k);
            float4 xv = *(const float4*)(xr + k);
            acc += xv.x * bfu2f(w.x) + xv.y * bfu2f(w.y)
                 + xv.z * bfu2f(w.z) + xv.w * bfu2f(w.w);
        }
    }
    xw[blockIdx.x * 4 * C + node * C + col] = acc;
}

// ---- GEMM2: xw2[n,c] = sum_k h[n,k] * W2[c,k]  (h f32, distinct buffers) --
__global__ __launch_bounds__(256) void k_gemm2(
    const float* __restrict__ h, const void* __restrict__ W,
    const int* __restrict__ flags, float* __restrict__ xw)
{
    __shared__ float xs[4 * C];
    int t = threadIdx.x;
    int base = blockIdx.x * 4 * C;
    xs[t] = h[base + t];
    __syncthreads();
    int node = t >> 6, col = t & 63;
    const float* xr = xs + node * C;
    float acc = 0.f;
    if (flags[0]) {
        const float* wr = (const float*)W + col * C;
        #pragma unroll
        for (int k = 0; k < C; k += 4) {
            float4 w = *(const float4*)(wr + k);
            float4 xv = *(const float4*)(xr + k);
            acc += xv.x * w.x + xv.y * w.y + xv.z * w.z + xv.w * w.w;
        }
    } else {
        const unsigned short* wr = (const unsigned short*)W + col * C;
        #pragma unroll
        for (int k = 0; k < C; k += 4) {
            ushort4 w = *(const ushort4*)(wr + k);
            float4 xv = *(const float4*)(xr + k);
            acc += xv.x * bfu2f(w.x) + xv.y * bfu2f(w.y)
                 + xv.z * bfu2f(w.z) + xv.w * bfu2f(w.w);
        }
    }
    xw[base + node * C + col] = acc;
}

// ---- fused msg+update: wave per dst, no atomics ---------------------------
// out = sigmoid( sum_e att_e * xw[src_e] + xw[d] + b )
__global__ __launch_bounds__(256) void k_msg_csr(
    const float* __restrict__ xw, const int2* __restrict__ srt,
    const int* __restrict__ row_ptr, const void* __restrict__ b,
    const int* __restrict__ flags, void* __restrict__ outp, int out_is_final)
{
    int d = blockIdx.x * 4 + (threadIdx.x >> 6);
    int lane = threadIdx.x & 63;
    int beg = row_ptr[d], end = row_ptr[d + 1];
    float acc = 0.f;
    int j = beg;
    for (; j + 4 <= end; j += 4) {
        int2 p0 = srt[j], p1 = srt[j + 1], p2 = srt[j + 2], p3 = srt[j + 3];
        float v0 = xw[(size_t)p0.x * C + lane];
        float v1 = xw[(size_t)p1.x * C + lane];
        float v2 = xw[(size_t)p2.x * C + lane];
        float v3 = xw[(size_t)p3.x * C + lane];
        acc += __int_as_float(p0.y) * v0 + __int_as_float(p1.y) * v1
             + __int_as_float(p2.y) * v2 + __int_as_float(p3.y) * v3;
    }
    for (; j < end; ++j) {
        int2 p = srt[j];
        acc += __int_as_float(p.y) * xw[(size_t)p.x * C + lane];
    }
    float v = acc + xw[(size_t)d * C + lane] + load_f(b, lane, flags[0]);
    float r = 1.f / (1.f + expf(-v));
    size_t oi = (size_t)d * C + lane;
    if (out_is_final) {
        if (flags[0]) ((float*)outp)[oi] = r;
        else ((__hip_bfloat16*)outp)[oi] = __float2bfloat16(r);
    } else {
        ((float*)outp)[oi] = r;
    }
}

extern "C" void kernel_launch(void* const* d_in, const int* in_sizes, int n_in,
                              void* d_out, int out_size, void* d_ws, size_t ws_size,
                              hipStream_t stream) {
    const void* x  = d_in[0];
    const void* ei = d_in[1];
    const void* ea = d_in[2];
    const void* W1 = d_in[3];
    const void* b1 = d_in[4];
    const void* W2 = d_in[5];
    const void* b2 = d_in[6];

    char* base = (char*)d_ws;
    int*   flags   = (int*)base;                        // 256 B
    float* ssum    = (float*)(base + 256);              // N
    int*   cnt     = (int*)(base + 400256);             // N
    int*   row_ptr = (int*)(base + 800256);             // N+1 (+pad)
    int*   next    = (int*)(base + 1200272);            // N
    int2*  srt     = (int2*)(base + 1600272);           // E (8B-aligned)
    float* xw      = (float*)(base + 14400272);         // N*64
    float* h1      = (float*)(base + 40000272);         // N*64
    // total ws use ≈ 65.6 MB

    k_detect<<<1, 256, 0, stream>>>((const unsigned short*)x, (const int*)ei, flags);
    hipMemsetAsync(ssum, 0, 800000, stream);            // ssum + cnt (contiguous)

    // CSR build (edge_attr/dst shared by both layers; att fully normalized)
    k_hist<<<N_EDGES / 256, 256, 0, stream>>>(ea, ei, flags, ssum, cnt);
    k_scan<<<1, 256, 0, stream>>>(cnt, row_ptr, next);
    k_scatter<<<N_EDGES / 256, 256, 0, stream>>>(ea, ei, flags, ssum, next, srt);

    // layer 1
    k_gemm1<<<N_NODES / 4, 256, 0, stream>>>(x, W1, flags, xw);
    k_msg_csr<<<N_NODES / 4, 256, 0, stream>>>(xw, srt, row_ptr, b1, flags, h1, 0);

    // layer 2
    k_gemm2<<<N_NODES / 4, 256, 0, stream>>>(h1, W2, flags, xw);
    k_msg_csr<<<N_NODES / 4, 256, 0, stream>>>(xw, srt, row_ptr, b2, flags, d_out, 1);
}

// Round 5
// 833.172 us; speedup vs baseline: 1.8349x; 1.5632x over previous
//
#include <hip/hip_runtime.h>
#include <hip/hip_bf16.h>

#define N_NODES 100000
#define N_EDGES 1600000
#define IN_C 128
#define C 64            // hid_c == out_c

__device__ __forceinline__ float bfu2f(unsigned short u) {
    return __uint_as_float(((unsigned int)u) << 16);
}
__device__ __forceinline__ float load_f(const void* p, int i, int f32) {
    return f32 ? ((const float*)p)[i] : bfu2f(((const unsigned short*)p)[i]);
}
__device__ __forceinline__ int load_idx(const void* ei, size_t i, int i64) {
    return i64 ? (int)((const long long*)ei)[i] : ((const int*)ei)[i];
}

// ---- runtime dtype detection (R3 confirmed bf16+int32; kept for safety) ---
__global__ __launch_bounds__(256) void k_detect(
    const unsigned short* __restrict__ x16, const int* __restrict__ ei32,
    int* __restrict__ flags)
{
    __shared__ int cff, cnz;
    int t = threadIdx.x;
    if (t == 0) { cff = 0; cnz = 0; }
    __syncthreads();
    int lff = 0;
    for (int i = t; i < 65536; i += 256) {
        unsigned short u = x16[i];
        if (((u >> 7) & 0xFF) == 0xFF) lff++;
    }
    int lnz = 0;
    for (int i = t; i < 2048; i += 256) {
        if (ei32[2 * i + 1] != 0) lnz++;
    }
    if (lff) atomicAdd(&cff, lff);
    if (lnz) atomicAdd(&cnz, lnz);
    __syncthreads();
    if (t == 0) {
        flags[0] = (cff > 0) ? 1 : 0;   // 1 = fp32 floats
        flags[1] = (cnz == 0) ? 1 : 0;  // 1 = int64 indices
    }
}

// ---- CSR pass A: degree histogram + softmax denominator -------------------
__global__ __launch_bounds__(256) void k_hist(
    const void* __restrict__ ea, const void* __restrict__ ei,
    const int* __restrict__ flags, float* __restrict__ ssum, int* __restrict__ cnt)
{
    int e = blockIdx.x * 256 + threadIdx.x;
    int d = load_idx(ei, (size_t)N_EDGES + e, flags[1]);
    atomicAdd(&ssum[d], expf(load_f(ea, e, flags[0])));
    atomicAdd(&cnt[d], 1);
}

// ---- CSR pass B: one-block exclusive scan cnt -> row_ptr, next ------------
__global__ __launch_bounds__(256) void k_scan(
    const int* __restrict__ cnt, int* __restrict__ row_ptr, int* __restrict__ next)
{
    __shared__ int part[256];
    int t = threadIdx.x;
    const int CH = (N_NODES + 255) / 256;   // 391
    int beg = t * CH, end = min(beg + CH, N_NODES);
    int s = 0;
    for (int i = beg; i < end; ++i) s += cnt[i];
    part[t] = s;
    for (int off = 1; off < 256; off <<= 1) {
        __syncthreads();
        int v = (t >= off) ? part[t - off] : 0;
        __syncthreads();
        part[t] += v;
    }
    __syncthreads();
    int run = (t == 0) ? 0 : part[t - 1];
    for (int i = beg; i < end; ++i) {
        row_ptr[i] = run; next[i] = run;
        run += cnt[i];
    }
    if (t == 255) row_ptr[N_NODES] = part[255];
}

// ---- CSR pass C: scatter {src, att} sorted by dst -------------------------
__global__ __launch_bounds__(256) void k_scatter(
    const void* __restrict__ ea, const void* __restrict__ ei,
    const int* __restrict__ flags, const float* __restrict__ ssum,
    int* __restrict__ next, int2* __restrict__ srt)
{
    int e = blockIdx.x * 256 + threadIdx.x;
    int s = load_idx(ei, (size_t)e, flags[1]);
    int d = load_idx(ei, (size_t)N_EDGES + e, flags[1]);
    float w = expf(load_f(ea, e, flags[0])) / ssum[d];
    int pos = atomicAdd(&next[d], 1);
    srt[pos] = make_int2(s, __float_as_int(w));
}

// ---- GEMM1: xw[n,c] = sum_k x[n,k] * W1[c,k] ------------------------------
// 32 nodes/block. W staged in LDS f32 with stride 132 (16B-aligned float4,
// quarter-wave conflict-free: lane i hits banks (4i+k)%32, 2-way = free).
// Wave w handles nodes 8w..8w+7; lane = col. xs reads are wave-broadcast.
#define W1_STRIDE (IN_C + 4)   // 132
__global__ __launch_bounds__(256) void k_gemm1(
    const void* __restrict__ x, const void* __restrict__ W,
    const int* __restrict__ flags, float* __restrict__ xw)
{
    __shared__ float Wls[C * W1_STRIDE];    // 64*132*4 = 33792 B
    __shared__ float xs[32 * IN_C];         // 16384 B
    int t = threadIdx.x;
    int f32 = flags[0];
    size_t xbase = (size_t)blockIdx.x * 32 * IN_C;
    if (f32) {
        const float* xp = (const float*)x + xbase;
        #pragma unroll
        for (int j = 0; j < 16; ++j) { int i = t + j * 256; xs[i] = xp[i]; }
        const float* wp = (const float*)W;
        #pragma unroll
        for (int j = 0; j < 32; ++j) {
            int i = t + j * 256;                 // 8192 elements
            Wls[(i >> 7) * W1_STRIDE + (i & 127)] = wp[i];
        }
    } else {
        const unsigned short* xp = (const unsigned short*)x + xbase;
        #pragma unroll
        for (int j = 0; j < 16; ++j) { int i = t + j * 256; xs[i] = bfu2f(xp[i]); }
        const unsigned short* wp = (const unsigned short*)W;
        #pragma unroll
        for (int j = 0; j < 32; ++j) {
            int i = t + j * 256;
            Wls[(i >> 7) * W1_STRIDE + (i & 127)] = bfu2f(wp[i]);
        }
    }
    __syncthreads();
    int col = t & 63, wv = t >> 6;
    const float* wr = Wls + col * W1_STRIDE;
    const float* xr = xs + wv * 8 * IN_C;
    float acc[8];
    #pragma unroll
    for (int n = 0; n < 8; ++n) acc[n] = 0.f;
    #pragma unroll
    for (int kk = 0; kk < IN_C / 4; ++kk) {
        float4 w4 = *(const float4*)(wr + kk * 4);
        #pragma unroll
        for (int n = 0; n < 8; ++n) {
            float4 x4 = *(const float4*)(xr + n * IN_C + kk * 4);
            acc[n] += x4.x * w4.x + x4.y * w4.y + x4.z * w4.z + x4.w * w4.w;
        }
    }
    size_t obase = (size_t)blockIdx.x * 32 * C + wv * 8 * C + col;
    #pragma unroll
    for (int n = 0; n < 8; ++n) xw[obase + n * C] = acc[n];
}

// ---- GEMM2: xw2[n,c] = sum_k h[n,k] * W2[c,k]  (h f32) --------------------
#define W2_STRIDE (C + 4)      // 68
__global__ __launch_bounds__(256) void k_gemm2(
    const float* __restrict__ h, const void* __restrict__ W,
    const int* __restrict__ flags, float* __restrict__ xw)
{
    __shared__ float Wls[C * W2_STRIDE];    // 64*68*4 = 17408 B
    __shared__ float xs[32 * C];            // 8192 B
    int t = threadIdx.x;
    size_t xbase = (size_t)blockIdx.x * 32 * C;
    #pragma unroll
    for (int j = 0; j < 8; ++j) { int i = t + j * 256; xs[i] = h[xbase + i]; }
    if (flags[0]) {
        const float* wp = (const float*)W;
        #pragma unroll
        for (int j = 0; j < 16; ++j) {
            int i = t + j * 256;                 // 4096 elements
            Wls[(i >> 6) * W2_STRIDE + (i & 63)] = wp[i];
        }
    } else {
        const unsigned short* wp = (const unsigned short*)W;
        #pragma unroll
        for (int j = 0; j < 16; ++j) {
            int i = t + j * 256;
            Wls[(i >> 6) * W2_STRIDE + (i & 63)] = bfu2f(wp[i]);
        }
    }
    __syncthreads();
    int col = t & 63, wv = t >> 6;
    const float* wr = Wls + col * W2_STRIDE;
    const float* xr = xs + wv * 8 * C;
    float acc[8];
    #pragma unroll
    for (int n = 0; n < 8; ++n) acc[n] = 0.f;
    #pragma unroll
    for (int kk = 0; kk < C / 4; ++kk) {
        float4 w4 = *(const float4*)(wr + kk * 4);
        #pragma unroll
        for (int n = 0; n < 8; ++n) {
            float4 x4 = *(const float4*)(xr + n * C + kk * 4);
            acc[n] += x4.x * w4.x + x4.y * w4.y + x4.z * w4.z + x4.w * w4.w;
        }
    }
    size_t obase = (size_t)blockIdx.x * 32 * C + wv * 8 * C + col;
    #pragma unroll
    for (int n = 0; n < 8; ++n) xw[obase + n * C] = acc[n];
}

// ---- fused msg+update: wave per dst, no atomics ---------------------------
// out = sigmoid( sum_e att_e * xw[src_e] + xw[d] + b )
__global__ __launch_bounds__(256) void k_msg_csr(
    const float* __restrict__ xw, const int2* __restrict__ srt,
    const int* __restrict__ row_ptr, const void* __restrict__ b,
    const int* __restrict__ flags, void* __restrict__ outp, int out_is_final)
{
    int d = blockIdx.x * 4 + (threadIdx.x >> 6);
    int lane = threadIdx.x & 63;
    int beg = row_ptr[d], end = row_ptr[d + 1];
    float acc = 0.f;
    int j = beg;
    for (; j + 4 <= end; j += 4) {
        int2 p0 = srt[j], p1 = srt[j + 1], p2 = srt[j + 2], p3 = srt[j + 3];
        float v0 = xw[(size_t)p0.x * C + lane];
        float v1 = xw[(size_t)p1.x * C + lane];
        float v2 = xw[(size_t)p2.x * C + lane];
        float v3 = xw[(size_t)p3.x * C + lane];
        acc += __int_as_float(p0.y) * v0 + __int_as_float(p1.y) * v1
             + __int_as_float(p2.y) * v2 + __int_as_float(p3.y) * v3;
    }
    for (; j < end; ++j) {
        int2 p = srt[j];
        acc += __int_as_float(p.y) * xw[(size_t)p.x * C + lane];
    }
    float v = acc + xw[(size_t)d * C + lane] + load_f(b, lane, flags[0]);
    float r = 1.f / (1.f + expf(-v));
    size_t oi = (size_t)d * C + lane;
    if (out_is_final) {
        if (flags[0]) ((float*)outp)[oi] = r;
        else ((__hip_bfloat16*)outp)[oi] = __float2bfloat16(r);
    } else {
        ((float*)outp)[oi] = r;
    }
}

extern "C" void kernel_launch(void* const* d_in, const int* in_sizes, int n_in,
                              void* d_out, int out_size, void* d_ws, size_t ws_size,
                              hipStream_t stream) {
    const void* x  = d_in[0];
    const void* ei = d_in[1];
    const void* ea = d_in[2];
    const void* W1 = d_in[3];
    const void* b1 = d_in[4];
    const void* W2 = d_in[5];
    const void* b2 = d_in[6];

    char* base = (char*)d_ws;
    int*   flags   = (int*)base;                        // 256 B
    float* ssum    = (float*)(base + 256);              // N
    int*   cnt     = (int*)(base + 400256);             // N
    int*   row_ptr = (int*)(base + 800256);             // N+1 (+pad)
    int*   next    = (int*)(base + 1200272);            // N
    int2*  srt     = (int2*)(base + 1600272);           // E (8B-aligned)
    float* xw      = (float*)(base + 14400272);         // N*64
    float* h1      = (float*)(base + 40000272);         // N*64
    // total ws use ≈ 65.6 MB

    k_detect<<<1, 256, 0, stream>>>((const unsigned short*)x, (const int*)ei, flags);
    hipMemsetAsync(ssum, 0, 800000, stream);            // ssum + cnt (contiguous)

    // CSR build (edge_attr/dst shared by both layers; att fully normalized)
    k_hist<<<N_EDGES / 256, 256, 0, stream>>>(ea, ei, flags, ssum, cnt);
    k_scan<<<1, 256, 0, stream>>>(cnt, row_ptr, next);
    k_scatter<<<N_EDGES / 256, 256, 0, stream>>>(ea, ei, flags, ssum, next, srt);

    // layer 1
    k_gemm1<<<N_NODES / 32, 256, 0, stream>>>(x, W1, flags, xw);
    k_msg_csr<<<N_NODES / 4, 256, 0, stream>>>(xw, srt, row_ptr, b1, flags, h1, 0);

    // layer 2
    k_gemm2<<<N_NODES / 32, 256, 0, stream>>>(h1, W2, flags, xw);
    k_msg_csr<<<N_NODES / 4, 256, 0, stream>>>(xw, srt, row_ptr, b2, flags, d_out, 1);
}

// Round 6
// 587.829 us; speedup vs baseline: 2.6007x; 1.4174x over previous
//
#include <hip/hip_runtime.h>
#include <hip/hip_bf16.h>

#define N_NODES 100000
#define N_EDGES 1600000
#define IN_C 128
#define C 64            // hid_c == out_c
#define SCAN_NB 25      // ceil(N_NODES / 4096)

__device__ __forceinline__ float bfu2f(unsigned short u) {
    return __uint_as_float(((unsigned int)u) << 16);
}
__device__ __forceinline__ float load_f(const void* p, int i, int f32) {
    return f32 ? ((const float*)p)[i] : bfu2f(((const unsigned short*)p)[i]);
}
__device__ __forceinline__ int load_idx(const void* ei, size_t i, int i64) {
    return i64 ? (int)((const long long*)ei)[i] : ((const int*)ei)[i];
}

// ---- runtime dtype detection (R3 confirmed bf16+int32; kept for safety) ---
// Vectorized: 64K ushorts of x as uint4 (P[fp32 undetected] ~ e^-128).
__global__ __launch_bounds__(256) void k_detect(
    const uint4* __restrict__ x4, const int* __restrict__ ei32,
    int* __restrict__ flags)
{
    __shared__ int cff, cnz;
    int t = threadIdx.x;
    if (t == 0) { cff = 0; cnz = 0; }
    __syncthreads();
    int lff = 0;
    #pragma unroll
    for (int j = 0; j < 16; ++j) {               // 4096 uint4 = 64K ushorts
        uint4 w = x4[t + j * 256];
        unsigned int a[4] = {w.x, w.y, w.z, w.w};
        #pragma unroll
        for (int q = 0; q < 4; ++q) {
            if ((a[q] & 0x00007F80u) == 0x00007F80u) lff++;
            if ((a[q] & 0x7F800000u) == 0x7F800000u) lff++;
        }
    }
    int lnz = 0;
    for (int i = t; i < 2048; i += 256)
        if (ei32[2 * i + 1] != 0) lnz++;
    if (lff) atomicAdd(&cff, lff);
    if (lnz) atomicAdd(&cnz, lnz);
    __syncthreads();
    if (t == 0) {
        flags[0] = (cff > 0) ? 1 : 0;   // 1 = fp32 floats
        flags[1] = (cnz == 0) ? 1 : 0;  // 1 = int64 indices
    }
}

// ---- CSR pass A: degree histogram + softmax denominator -------------------
__global__ __launch_bounds__(256) void k_hist(
    const void* __restrict__ ea, const void* __restrict__ ei,
    const int* __restrict__ flags, float* __restrict__ ssum, int* __restrict__ cnt)
{
    int e = blockIdx.x * 256 + threadIdx.x;
    int d = load_idx(ei, (size_t)N_EDGES + e, flags[1]);
    atomicAdd(&ssum[d], expf(load_f(ea, e, flags[0])));
    atomicAdd(&cnt[d], 1);
}

// ---- CSR pass B1: per-block sums of cnt (4096 elems/block, coalesced) -----
__global__ __launch_bounds__(256) void k_scan1(
    const int* __restrict__ cnt, int* __restrict__ bsum)
{
    __shared__ int red[256];
    int t = threadIdx.x, b = blockIdx.x;
    int base = b * 4096;
    int s = 0;
    #pragma unroll
    for (int j = 0; j < 16; ++j) {
        int i = base + j * 256 + t;
        if (i < N_NODES) s += cnt[i];
    }
    red[t] = s;
    #pragma unroll
    for (int off = 128; off > 0; off >>= 1) {
        __syncthreads();
        if (t < off) red[t] += red[t + off];
    }
    if (t == 0) bsum[b] = red[0];
}

// ---- CSR pass B2: per-block exclusive scan -> row_ptr, next ---------------
__global__ __launch_bounds__(256) void k_scan3(
    const int* __restrict__ cnt, const int* __restrict__ bsum,
    int* __restrict__ row_ptr, int* __restrict__ next)
{
    __shared__ int tsum[256];
    __shared__ int off_sh;
    int t = threadIdx.x, b = blockIdx.x;
    if (t == 0) {
        int o = 0;
        for (int i = 0; i < b; ++i) o += bsum[i];
        off_sh = o;
        if (b == 0) row_ptr[N_NODES] = N_EDGES;   // total is a constant
    }
    int base = b * 4096 + t * 16;
    int v[16], s = 0;
    #pragma unroll
    for (int j = 0; j < 16; ++j) {
        int i = base + j;
        v[j] = (i < N_NODES) ? cnt[i] : 0;
        s += v[j];
    }
    tsum[t] = s;
    #pragma unroll
    for (int off = 1; off < 256; off <<= 1) {
        __syncthreads();
        int val = (t >= off) ? tsum[t - off] : 0;
        __syncthreads();
        tsum[t] += val;
    }
    __syncthreads();
    int run = off_sh + (t ? tsum[t - 1] : 0);
    #pragma unroll
    for (int j = 0; j < 16; ++j) {
        int i = base + j;
        if (i < N_NODES) { row_ptr[i] = run; next[i] = run; run += v[j]; }
    }
}

// ---- CSR pass C: scatter {src, att} sorted by dst -------------------------
__global__ __launch_bounds__(256) void k_scatter(
    const void* __restrict__ ea, const void* __restrict__ ei,
    const int* __restrict__ flags, const float* __restrict__ ssum,
    int* __restrict__ next, int2* __restrict__ srt)
{
    int e = blockIdx.x * 256 + threadIdx.x;
    int s = load_idx(ei, (size_t)e, flags[1]);
    int d = load_idx(ei, (size_t)N_EDGES + e, flags[1]);
    float w = expf(load_f(ea, e, flags[0])) / ssum[d];
    int pos = atomicAdd(&next[d], 1);
    srt[pos] = make_int2(s, __float_as_int(w));
}

// ---- GEMM1: xw[n,c] = sum_k x[n,k] * W1[c,k] ------------------------------
// 32 nodes/block; W staged in LDS (stride 132: float4-aligned, conflict-free).
#define W1_STRIDE (IN_C + 4)   // 132
__global__ __launch_bounds__(256) void k_gemm1(
    const void* __restrict__ x, const void* __restrict__ W,
    const int* __restrict__ flags, float* __restrict__ xw)
{
    __shared__ float Wls[C * W1_STRIDE];    // 33792 B
    __shared__ float xs[32 * IN_C];         // 16384 B
    int t = threadIdx.x;
    int f32 = flags[0];
    size_t xbase = (size_t)blockIdx.x * 32 * IN_C;
    if (f32) {
        const float* xp = (const float*)x + xbase;
        #pragma unroll
        for (int j = 0; j < 16; ++j) { int i = t + j * 256; xs[i] = xp[i]; }
        const float* wp = (const float*)W;
        #pragma unroll
        for (int j = 0; j < 32; ++j) {
            int i = t + j * 256;
            Wls[(i >> 7) * W1_STRIDE + (i & 127)] = wp[i];
        }
    } else {
        const unsigned short* xp = (const unsigned short*)x + xbase;
        #pragma unroll
        for (int j = 0; j < 16; ++j) { int i = t + j * 256; xs[i] = bfu2f(xp[i]); }
        const unsigned short* wp = (const unsigned short*)W;
        #pragma unroll
        for (int j = 0; j < 32; ++j) {
            int i = t + j * 256;
            Wls[(i >> 7) * W1_STRIDE + (i & 127)] = bfu2f(wp[i]);
        }
    }
    __syncthreads();
    int col = t & 63, wv = t >> 6;
    const float* wr = Wls + col * W1_STRIDE;
    const float* xr = xs + wv * 8 * IN_C;
    float acc[8];
    #pragma unroll
    for (int n = 0; n < 8; ++n) acc[n] = 0.f;
    #pragma unroll
    for (int kk = 0; kk < IN_C / 4; ++kk) {
        float4 w4 = *(const float4*)(wr + kk * 4);
        #pragma unroll
        for (int n = 0; n < 8; ++n) {
            float4 x4 = *(const float4*)(xr + n * IN_C + kk * 4);
            acc[n] += x4.x * w4.x + x4.y * w4.y + x4.z * w4.z + x4.w * w4.w;
        }
    }
    size_t obase = (size_t)blockIdx.x * 32 * C + wv * 8 * C + col;
    #pragma unroll
    for (int n = 0; n < 8; ++n) xw[obase + n * C] = acc[n];
}

// ---- GEMM2: xw2[n,c] = sum_k h[n,k] * W2[c,k]  (h f32) --------------------
#define W2_STRIDE (C + 4)      // 68
__global__ __launch_bounds__(256) void k_gemm2(
    const float* __restrict__ h, const void* __restrict__ W,
    const int* __restrict__ flags, float* __restrict__ xw)
{
    __shared__ float Wls[C * W2_STRIDE];
    __shared__ float xs[32 * C];
    int t = threadIdx.x;
    size_t xbase = (size_t)blockIdx.x * 32 * C;
    #pragma unroll
    for (int j = 0; j < 8; ++j) { int i = t + j * 256; xs[i] = h[xbase + i]; }
    if (flags[0]) {
        const float* wp = (const float*)W;
        #pragma unroll
        for (int j = 0; j < 16; ++j) {
            int i = t + j * 256;
            Wls[(i >> 6) * W2_STRIDE + (i & 63)] = wp[i];
        }
    } else {
        const unsigned short* wp = (const unsigned short*)W;
        #pragma unroll
        for (int j = 0; j < 16; ++j) {
            int i = t + j * 256;
            Wls[(i >> 6) * W2_STRIDE + (i & 63)] = bfu2f(wp[i]);
        }
    }
    __syncthreads();
    int col = t & 63, wv = t >> 6;
    const float* wr = Wls + col * W2_STRIDE;
    const float* xr = xs + wv * 8 * C;
    float acc[8];
    #pragma unroll
    for (int n = 0; n < 8; ++n) acc[n] = 0.f;
    #pragma unroll
    for (int kk = 0; kk < C / 4; ++kk) {
        float4 w4 = *(const float4*)(wr + kk * 4);
        #pragma unroll
        for (int n = 0; n < 8; ++n) {
            float4 x4 = *(const float4*)(xr + n * C + kk * 4);
            acc[n] += x4.x * w4.x + x4.y * w4.y + x4.z * w4.z + x4.w * w4.w;
        }
    }
    size_t obase = (size_t)blockIdx.x * 32 * C + wv * 8 * C + col;
    #pragma unroll
    for (int n = 0; n < 8; ++n) xw[obase + n * C] = acc[n];
}

// ---- fused msg+update: wave per dst, no atomics ---------------------------
__global__ __launch_bounds__(256) void k_msg_csr(
    const float* __restrict__ xw, const int2* __restrict__ srt,
    const int* __restrict__ row_ptr, const void* __restrict__ b,
    const int* __restrict__ flags, void* __restrict__ outp, int out_is_final)
{
    int d = blockIdx.x * 4 + (threadIdx.x >> 6);
    int lane = threadIdx.x & 63;
    int beg = row_ptr[d], end = row_ptr[d + 1];
    float acc = 0.f;
    int j = beg;
    for (; j + 4 <= end; j += 4) {
        int2 p0 = srt[j], p1 = srt[j + 1], p2 = srt[j + 2], p3 = srt[j + 3];
        float v0 = xw[(size_t)p0.x * C + lane];
        float v1 = xw[(size_t)p1.x * C + lane];
        float v2 = xw[(size_t)p2.x * C + lane];
        float v3 = xw[(size_t)p3.x * C + lane];
        acc += __int_as_float(p0.y) * v0 + __int_as_float(p1.y) * v1
             + __int_as_float(p2.y) * v2 + __int_as_float(p3.y) * v3;
    }
    for (; j < end; ++j) {
        int2 p = srt[j];
        acc += __int_as_float(p.y) * xw[(size_t)p.x * C + lane];
    }
    float v = acc + xw[(size_t)d * C + lane] + load_f(b, lane, flags[0]);
    float r = 1.f / (1.f + expf(-v));
    size_t oi = (size_t)d * C + lane;
    if (out_is_final) {
        if (flags[0]) ((float*)outp)[oi] = r;
        else ((__hip_bfloat16*)outp)[oi] = __float2bfloat16(r);
    } else {
        ((float*)outp)[oi] = r;
    }
}

extern "C" void kernel_launch(void* const* d_in, const int* in_sizes, int n_in,
                              void* d_out, int out_size, void* d_ws, size_t ws_size,
                              hipStream_t stream) {
    const void* x  = d_in[0];
    const void* ei = d_in[1];
    const void* ea = d_in[2];
    const void* W1 = d_in[3];
    const void* b1 = d_in[4];
    const void* W2 = d_in[5];
    const void* b2 = d_in[6];

    char* base = (char*)d_ws;
    int*   flags   = (int*)base;                        // 256 B
    float* ssum    = (float*)(base + 256);              // N
    int*   cnt     = (int*)(base + 400256);             // N
    int*   row_ptr = (int*)(base + 800256);             // N+1 (+pad)
    int*   next    = (int*)(base + 1200272);            // N
    int*   bsum    = (int*)(base + 1600272);            // 25 (+pad to 8B)
    int2*  srt     = (int2*)(base + 1600528);           // E (8B-aligned)
    float* xw      = (float*)(base + 14400528);         // N*64
    float* h1      = (float*)(base + 40000528);         // N*64
    // total ws use ≈ 65.6 MB

    k_detect<<<1, 256, 0, stream>>>((const uint4*)x, (const int*)ei, flags);
    hipMemsetAsync(ssum, 0, 800000, stream);            // ssum + cnt (contiguous)

    // CSR build (edge_attr/dst shared by both layers; att fully normalized)
    k_hist<<<N_EDGES / 256, 256, 0, stream>>>(ea, ei, flags, ssum, cnt);
    k_scan1<<<SCAN_NB, 256, 0, stream>>>(cnt, bsum);
    k_scan3<<<SCAN_NB, 256, 0, stream>>>(cnt, bsum, row_ptr, next);
    k_scatter<<<N_EDGES / 256, 256, 0, stream>>>(ea, ei, flags, ssum, next, srt);

    // layer 1
    k_gemm1<<<N_NODES / 32, 256, 0, stream>>>(x, W1, flags, xw);
    k_msg_csr<<<N_NODES / 4, 256, 0, stream>>>(xw, srt, row_ptr, b1, flags, h1, 0);

    // layer 2
    k_gemm2<<<N_NODES / 32, 256, 0, stream>>>(h1, W2, flags, xw);
    k_msg_csr<<<N_NODES / 4, 256, 0, stream>>>(xw, srt, row_ptr, b2, flags, d_out, 1);
}

// Round 7
// 441.012 us; speedup vs baseline: 3.4665x; 1.3329x over previous
//
#include <hip/hip_runtime.h>
#include <hip/hip_bf16.h>

#define N_NODES 100000
#define N_EDGES 1600000
#define IN_C 128
#define C 64            // hid_c == out_c
#define SCAN_NB 25      // ceil(N_NODES / 4096)

__device__ __forceinline__ float bfu2f(unsigned short u) {
    return __uint_as_float(((unsigned int)u) << 16);
}
__device__ __forceinline__ float load_f(const void* p, int i, int f32) {
    return f32 ? ((const float*)p)[i] : bfu2f(((const unsigned short*)p)[i]);
}
__device__ __forceinline__ int load_idx(const void* ei, size_t i, int i64) {
    return i64 ? (int)((const long long*)ei)[i] : ((const int*)ei)[i];
}

// ---- runtime dtype detection (R3 confirmed bf16+int32; kept for safety) ---
__global__ __launch_bounds__(256) void k_detect(
    const uint4* __restrict__ x4, const int* __restrict__ ei32,
    int* __restrict__ flags)
{
    __shared__ int cff, cnz;
    int t = threadIdx.x;
    if (t == 0) { cff = 0; cnz = 0; }
    __syncthreads();
    int lff = 0;
    #pragma unroll
    for (int j = 0; j < 16; ++j) {               // 4096 uint4 = 64K ushorts
        uint4 w = x4[t + j * 256];
        unsigned int a[4] = {w.x, w.y, w.z, w.w};
        #pragma unroll
        for (int q = 0; q < 4; ++q) {
            if ((a[q] & 0x00007F80u) == 0x00007F80u) lff++;
            if ((a[q] & 0x7F800000u) == 0x7F800000u) lff++;
        }
    }
    int lnz = 0;
    for (int i = t; i < 2048; i += 256)
        if (ei32[2 * i + 1] != 0) lnz++;
    if (lff) atomicAdd(&cff, lff);
    if (lnz) atomicAdd(&cnz, lnz);
    __syncthreads();
    if (t == 0) {
        flags[0] = (cff > 0) ? 1 : 0;   // 1 = fp32 floats
        flags[1] = (cnz == 0) ? 1 : 0;  // 1 = int64 indices
    }
}

// ---- CSR pass A: degree count + within-segment position (ONE atomic/edge) -
__global__ __launch_bounds__(256) void k_hist(
    const void* __restrict__ ei, const int* __restrict__ flags,
    int* __restrict__ cnt, unsigned short* __restrict__ pos)
{
    int e = blockIdx.x * 256 + threadIdx.x;
    int d = load_idx(ei, (size_t)N_EDGES + e, flags[1]);
    pos[e] = (unsigned short)atomicAdd(&cnt[d], 1);
}

// ---- CSR pass B1: per-block sums of cnt (coalesced) -----------------------
__global__ __launch_bounds__(256) void k_scan1(
    const int* __restrict__ cnt, int* __restrict__ bsum)
{
    __shared__ int red[256];
    int t = threadIdx.x, b = blockIdx.x;
    int base = b * 4096;
    int s = 0;
    #pragma unroll
    for (int j = 0; j < 16; ++j) {
        int i = base + j * 256 + t;
        if (i < N_NODES) s += cnt[i];
    }
    red[t] = s;
    #pragma unroll
    for (int off = 128; off > 0; off >>= 1) {
        __syncthreads();
        if (t < off) red[t] += red[t + off];
    }
    if (t == 0) bsum[b] = red[0];
}

// ---- CSR pass B2: per-block exclusive scan -> row_ptr ---------------------
__global__ __launch_bounds__(256) void k_scan3(
    const int* __restrict__ cnt, const int* __restrict__ bsum,
    int* __restrict__ row_ptr)
{
    __shared__ int tsum[256];
    __shared__ int off_sh;
    int t = threadIdx.x, b = blockIdx.x;
    if (t == 0) {
        int o = 0;
        for (int i = 0; i < b; ++i) o += bsum[i];
        off_sh = o;
        if (b == 0) row_ptr[N_NODES] = N_EDGES;   // total is a constant
    }
    int base = b * 4096 + t * 16;
    int v[16], s = 0;
    #pragma unroll
    for (int j = 0; j < 16; ++j) {
        int i = base + j;
        v[j] = (i < N_NODES) ? cnt[i] : 0;
        s += v[j];
    }
    tsum[t] = s;
    #pragma unroll
    for (int off = 1; off < 256; off <<= 1) {
        __syncthreads();
        int val = (t >= off) ? tsum[t - off] : 0;
        __syncthreads();
        tsum[t] += val;
    }
    __syncthreads();
    int run = off_sh + (t ? tsum[t - 1] : 0);
    #pragma unroll
    for (int j = 0; j < 16; ++j) {
        int i = base + j;
        if (i < N_NODES) { row_ptr[i] = run; run += v[j]; }
    }
}

// ---- CSR pass C: scatter {src, raw exp} — NO atomics ----------------------
__global__ __launch_bounds__(256) void k_scatter(
    const void* __restrict__ ea, const void* __restrict__ ei,
    const int* __restrict__ flags, const int* __restrict__ row_ptr,
    const unsigned short* __restrict__ pos, int2* __restrict__ srt)
{
    int e = blockIdx.x * 256 + threadIdx.x;
    int s = load_idx(ei, (size_t)e, flags[1]);
    int d = load_idx(ei, (size_t)N_EDGES + e, flags[1]);
    float w = expf(load_f(ea, e, flags[0]));     // unnormalized
    int p = row_ptr[d] + pos[e];
    srt[p] = make_int2(s, __float_as_int(w));
}

// ---- GEMM1: xw[n,c] = sum_k x[n,k] * W1[c,k] ------------------------------
#define W1_STRIDE (IN_C + 4)   // 132
__global__ __launch_bounds__(256) void k_gemm1(
    const void* __restrict__ x, const void* __restrict__ W,
    const int* __restrict__ flags, float* __restrict__ xw)
{
    __shared__ float Wls[C * W1_STRIDE];
    __shared__ float xs[32 * IN_C];
    int t = threadIdx.x;
    int f32 = flags[0];
    size_t xbase = (size_t)blockIdx.x * 32 * IN_C;
    if (f32) {
        const float* xp = (const float*)x + xbase;
        #pragma unroll
        for (int j = 0; j < 16; ++j) { int i = t + j * 256; xs[i] = xp[i]; }
        const float* wp = (const float*)W;
        #pragma unroll
        for (int j = 0; j < 32; ++j) {
            int i = t + j * 256;
            Wls[(i >> 7) * W1_STRIDE + (i & 127)] = wp[i];
        }
    } else {
        const unsigned short* xp = (const unsigned short*)x + xbase;
        #pragma unroll
        for (int j = 0; j < 16; ++j) { int i = t + j * 256; xs[i] = bfu2f(xp[i]); }
        const unsigned short* wp = (const unsigned short*)W;
        #pragma unroll
        for (int j = 0; j < 32; ++j) {
            int i = t + j * 256;
            Wls[(i >> 7) * W1_STRIDE + (i & 127)] = bfu2f(wp[i]);
        }
    }
    __syncthreads();
    int col = t & 63, wv = t >> 6;
    const float* wr = Wls + col * W1_STRIDE;
    const float* xr = xs + wv * 8 * IN_C;
    float acc[8];
    #pragma unroll
    for (int n = 0; n < 8; ++n) acc[n] = 0.f;
    #pragma unroll
    for (int kk = 0; kk < IN_C / 4; ++kk) {
        float4 w4 = *(const float4*)(wr + kk * 4);
        #pragma unroll
        for (int n = 0; n < 8; ++n) {
            float4 x4 = *(const float4*)(xr + n * IN_C + kk * 4);
            acc[n] += x4.x * w4.x + x4.y * w4.y + x4.z * w4.z + x4.w * w4.w;
        }
    }
    size_t obase = (size_t)blockIdx.x * 32 * C + wv * 8 * C + col;
    #pragma unroll
    for (int n = 0; n < 8; ++n) xw[obase + n * C] = acc[n];
}

// ---- GEMM2: xw2[n,c] = sum_k h[n,k] * W2[c,k]  (h f32) --------------------
#define W2_STRIDE (C + 4)      // 68
__global__ __launch_bounds__(256) void k_gemm2(
    const float* __restrict__ h, const void* __restrict__ W,
    const int* __restrict__ flags, float* __restrict__ xw)
{
    __shared__ float Wls[C * W2_STRIDE];
    __shared__ float xs[32 * C];
    int t = threadIdx.x;
    size_t xbase = (size_t)blockIdx.x * 32 * C;
    #pragma unroll
    for (int j = 0; j < 8; ++j) { int i = t + j * 256; xs[i] = h[xbase + i]; }
    if (flags[0]) {
        const float* wp = (const float*)W;
        #pragma unroll
        for (int j = 0; j < 16; ++j) {
            int i = t + j * 256;
            Wls[(i >> 6) * W2_STRIDE + (i & 63)] = wp[i];
        }
    } else {
        const unsigned short* wp = (const unsigned short*)W;
        #pragma unroll
        for (int j = 0; j < 16; ++j) {
            int i = t + j * 256;
            Wls[(i >> 6) * W2_STRIDE + (i & 63)] = bfu2f(wp[i]);
        }
    }
    __syncthreads();
    int col = t & 63, wv = t >> 6;
    const float* wr = Wls + col * W2_STRIDE;
    const float* xr = xs + wv * 8 * C;
    float acc[8];
    #pragma unroll
    for (int n = 0; n < 8; ++n) acc[n] = 0.f;
    #pragma unroll
    for (int kk = 0; kk < C / 4; ++kk) {
        float4 w4 = *(const float4*)(wr + kk * 4);
        #pragma unroll
        for (int n = 0; n < 8; ++n) {
            float4 x4 = *(const float4*)(xr + n * C + kk * 4);
            acc[n] += x4.x * w4.x + x4.y * w4.y + x4.z * w4.z + x4.w * w4.w;
        }
    }
    size_t obase = (size_t)blockIdx.x * 32 * C + wv * 8 * C + col;
    #pragma unroll
    for (int n = 0; n < 8; ++n) xw[obase + n * C] = acc[n];
}

// ---- fused msg+update: wave per dst; self-normalizing (no ssum pass) ------
// out = sigmoid( (Σ exp_e·xw[src_e]) / (Σ exp_e) + xw[d] + b )
__global__ __launch_bounds__(256) void k_msg_csr(
    const float* __restrict__ xw, const int2* __restrict__ srt,
    const int* __restrict__ row_ptr, const void* __restrict__ b,
    const int* __restrict__ flags, void* __restrict__ outp, int out_is_final)
{
    int d = blockIdx.x * 4 + (threadIdx.x >> 6);
    int lane = threadIdx.x & 63;
    int beg = row_ptr[d], end = row_ptr[d + 1];
    float acc = 0.f, asum = 0.f;
    int j = beg;
    for (; j + 4 <= end; j += 4) {
        int2 p0 = srt[j], p1 = srt[j + 1], p2 = srt[j + 2], p3 = srt[j + 3];
        float w0 = __int_as_float(p0.y), w1 = __int_as_float(p1.y);
        float w2 = __int_as_float(p2.y), w3 = __int_as_float(p3.y);
        acc += w0 * xw[(size_t)p0.x * C + lane]
             + w1 * xw[(size_t)p1.x * C + lane]
             + w2 * xw[(size_t)p2.x * C + lane]
             + w3 * xw[(size_t)p3.x * C + lane];
        asum += (w0 + w1) + (w2 + w3);
    }
    for (; j < end; ++j) {
        int2 p = srt[j];
        float w = __int_as_float(p.y);
        acc += w * xw[(size_t)p.x * C + lane];
        asum += w;
    }
    float m = (end > beg) ? acc / asum : 0.f;
    float v = m + xw[(size_t)d * C + lane] + load_f(b, lane, flags[0]);
    float r = 1.f / (1.f + expf(-v));
    size_t oi = (size_t)d * C + lane;
    if (out_is_final) {
        if (flags[0]) ((float*)outp)[oi] = r;
        else ((__hip_bfloat16*)outp)[oi] = __float2bfloat16(r);
    } else {
        ((float*)outp)[oi] = r;
    }
}

extern "C" void kernel_launch(void* const* d_in, const int* in_sizes, int n_in,
                              void* d_out, int out_size, void* d_ws, size_t ws_size,
                              hipStream_t stream) {
    const void* x  = d_in[0];
    const void* ei = d_in[1];
    const void* ea = d_in[2];
    const void* W1 = d_in[3];
    const void* b1 = d_in[4];
    const void* W2 = d_in[5];
    const void* b2 = d_in[6];

    char* base = (char*)d_ws;
    int*            flags   = (int*)base;                 // 256 B
    int*            cnt     = (int*)(base + 256);         // N
    int*            row_ptr = (int*)(base + 400256);      // N+1 (+pad)
    unsigned short* pos     = (unsigned short*)(base + 800272);  // E (2B)
    int*            bsum    = (int*)(base + 4000272);     // 25 (+pad)
    int2*           srt     = (int2*)(base + 4000528);    // E (8B-aligned)
    float*          xw      = (float*)(base + 16800528);  // N*64
    float*          h1      = (float*)(base + 42400528);  // N*64
    // total ws use ≈ 68 MB

    k_detect<<<1, 256, 0, stream>>>((const uint4*)x, (const int*)ei, flags);
    hipMemsetAsync(cnt, 0, 400000, stream);

    // CSR build: count+pos (1 atomic/edge), scan, atomic-free scatter
    k_hist<<<N_EDGES / 256, 256, 0, stream>>>(ei, flags, cnt, pos);
    k_scan1<<<SCAN_NB, 256, 0, stream>>>(cnt, bsum);
    k_scan3<<<SCAN_NB, 256, 0, stream>>>(cnt, bsum, row_ptr);
    k_scatter<<<N_EDGES / 256, 256, 0, stream>>>(ea, ei, flags, row_ptr, pos, srt);

    // layer 1
    k_gemm1<<<N_NODES / 32, 256, 0, stream>>>(x, W1, flags, xw);
    k_msg_csr<<<N_NODES / 4, 256, 0, stream>>>(xw, srt, row_ptr, b1, flags, h1, 0);

    // layer 2
    k_gemm2<<<N_NODES / 32, 256, 0, stream>>>(h1, W2, flags, xw);
    k_msg_csr<<<N_NODES / 4, 256, 0, stream>>>(xw, srt, row_ptr, b2, flags, d_out, 1);
}